// Round 7
// baseline (184.400 us; speedup 1.0000x reference)
//
#include <hip/hip_runtime.h>

// Problem constants
#define BB 16
#define SS 2048
#define DD 768
#define D4 192
#define MSTRIDE 2052          // meta row stride in ints (16B-aligned rows)

typedef float vfloat4 __attribute__((ext_vector_type(4)));

// K0: meta[b][w] = lower_bound(seg[b,:], w), for w in [0, SS] inclusive.
// Slot-parallel: 11 LDS probes per thread, 33K threads -> latency fully
// throughput-hidden. count(w) = meta[w+1] - meta[w] in K_main.
__global__ __launch_bounds__(256) void build_meta(const int* __restrict__ seg,
                                                  int* __restrict__ meta) {
    __shared__ int srow[SS];
    const int b = blockIdx.y;
    const int4* g = (const int4*)(seg + b * SS);
    for (int i = threadIdx.x; i < SS / 4; i += 256) ((int4*)srow)[i] = g[i];
    __syncthreads();

    int w = blockIdx.x * 256 + threadIdx.x;
    if (w > SS) return;
    int lo = 0, n = SS;
    while (n > 0) {
        int half = n >> 1, mid = lo + half;
        if (srow[mid] < w) { lo = mid + 1; n -= half + 1; }
        else               { n = half; }
    }
    meta[b * MSTRIDE + w] = lo;
}

// K_main: wave = 4 consecutive output slots; lane t owns float4-cols t,t+64,t+128.
// Meta via 2 broadcast loads; row-0 of all 4 slots prefetched up front so the
// wave starts with 12 independent dwordx4 in flight; no LDS, no scans.
__global__ __launch_bounds__(256) void seg_mean_v7(const float* __restrict__ x,
                                                   const int* __restrict__ meta,
                                                   float* __restrict__ out) {
    const int b    = blockIdx.y;
    const int lane = threadIdx.x & 63;
    const int wave = threadIdx.x >> 6;
    const int w0   = (blockIdx.x << 4) + (wave << 2);

    const int* mp = meta + b * MSTRIDE + w0;
    int4 m4 = *(const int4*)mp;          // broadcast (all lanes same addr)
    int  m5 = mp[4];
    int st[5] = {m4.x, m4.y, m4.z, m4.w, m5};

    const float* xbase = x + (size_t)b * SS * DD;
    float*       obase = out + (size_t)b * SS * DD;

    // Up-front prefetch: first row of each slot (dummy row 0 if empty).
    vfloat4 p[4][3];
    #pragma unroll
    for (int s = 0; s < 4; ++s) {
        int r = (st[s] < st[s + 1]) ? st[s] : 0;
        const vfloat4* xr = (const vfloat4*)(xbase + (size_t)r * DD);
        p[s][0] = xr[lane]; p[s][1] = xr[lane + 64]; p[s][2] = xr[lane + 128];
    }

    #pragma unroll
    for (int s = 0; s < 4; ++s) {
        vfloat4* op = (vfloat4*)(obase + (size_t)(w0 + s) * DD);
        int c = st[s + 1] - st[s];
        if (c == 0) {
            vfloat4 z = {0.f, 0.f, 0.f, 0.f};
            __builtin_nontemporal_store(z, &op[lane]);
            __builtin_nontemporal_store(z, &op[lane + 64]);
            __builtin_nontemporal_store(z, &op[lane + 128]);
            continue;
        }
        vfloat4 a0 = p[s][0], a1 = p[s][1], a2 = p[s][2];
        for (int j = 1; j < c; ++j) {
            const vfloat4* xr = (const vfloat4*)(xbase + (size_t)(st[s] + j) * DD);
            a0 += xr[lane]; a1 += xr[lane + 64]; a2 += xr[lane + 128];
        }
        float inv = 1.0f / (float)c;
        __builtin_nontemporal_store(a0 * inv, &op[lane]);
        __builtin_nontemporal_store(a1 * inv, &op[lane + 64]);
        __builtin_nontemporal_store(a2 * inv, &op[lane + 128]);
    }
}

extern "C" void kernel_launch(void* const* d_in, const int* in_sizes, int n_in,
                              void* d_out, int out_size, void* d_ws, size_t ws_size,
                              hipStream_t stream) {
    const float* x   = (const float*)d_in[0];   // [B,S,D] fp32
    const int*   seg = (const int*)d_in[1];     // [B,S] int32
    float* out  = (float*)d_out;                // [B,S,D] fp32
    int*   meta = (int*)d_ws;                   // BB * MSTRIDE ints (~131 KB)

    dim3 g0((SS + 1 + 255) / 256, BB);          // 9 x 16 blocks
    build_meta<<<g0, 256, 0, stream>>>(seg, meta);

    dim3 g1(SS / 16, BB);                       // 128 x 16 = 2048 blocks
    seg_mean_v7<<<g1, 256, 0, stream>>>(x, meta, out);
}